// Round 3
// baseline (213.492 us; speedup 1.0000x reference)
//
#include <hip/hip_runtime.h>

// Problem constants (match reference)
#define T_DIM 4096
#define B_DIM 256
// N_OBS=64, H=8, N_ACT=18

template<int N> struct IC { static constexpr int value = N; };

// ---------------------------------------------------------------------------
// Kernel A: fused MLP  states(B,T,64) -> x1(4) -> x2(B,T,8), relu
// One thread per (b,t) row. Weights in LDS (uniform broadcast reads).
// ---------------------------------------------------------------------------
__global__ __launch_bounds__(256) void mlp_kernel(
    const float* __restrict__ states,
    const float* __restrict__ W1, const float* __restrict__ b1,
    const float* __restrict__ W2, const float* __restrict__ b2,
    float* __restrict__ x2out)
{
    __shared__ float w1s[4][64];
    __shared__ float w2s[8][4];
    __shared__ float biass[12]; // b1[0..3], b2[0..7]
    int tid = threadIdx.x;
    w1s[tid >> 6][tid & 63] = W1[tid];          // 256 elements
    if (tid < 32) w2s[tid >> 2][tid & 3] = W2[tid];
    if (tid < 4)  biass[tid] = b1[tid];
    if (tid >= 4 && tid < 12) biass[tid] = b2[tid - 4];
    __syncthreads();

    size_t r = (size_t)blockIdx.x * 256 + tid;   // row in [0, B*T)
    const float4* src = (const float4*)(states + r * 64);

    float a0 = biass[0], a1 = biass[1], a2 = biass[2], a3 = biass[3];
#pragma unroll
    for (int k = 0; k < 16; ++k) {
        float4 v = src[k];
        float4 w;
        w = ((const float4*)w1s[0])[k];
        a0 = fmaf(v.x, w.x, a0); a0 = fmaf(v.y, w.y, a0);
        a0 = fmaf(v.z, w.z, a0); a0 = fmaf(v.w, w.w, a0);
        w = ((const float4*)w1s[1])[k];
        a1 = fmaf(v.x, w.x, a1); a1 = fmaf(v.y, w.y, a1);
        a1 = fmaf(v.z, w.z, a1); a1 = fmaf(v.w, w.w, a1);
        w = ((const float4*)w1s[2])[k];
        a2 = fmaf(v.x, w.x, a2); a2 = fmaf(v.y, w.y, a2);
        a2 = fmaf(v.z, w.z, a2); a2 = fmaf(v.w, w.w, a2);
        w = ((const float4*)w1s[3])[k];
        a3 = fmaf(v.x, w.x, a3); a3 = fmaf(v.y, w.y, a3);
        a3 = fmaf(v.z, w.z, a3); a3 = fmaf(v.w, w.w, a3);
    }
    a0 = fmaxf(a0, 0.f); a1 = fmaxf(a1, 0.f);
    a2 = fmaxf(a2, 0.f); a3 = fmaxf(a3, 0.f);

    float x2v[8];
#pragma unroll
    for (int hh = 0; hh < 8; ++hh) {
        float s = biass[4 + hh];
        s = fmaf(a0, w2s[hh][0], s);
        s = fmaf(a1, w2s[hh][1], s);
        s = fmaf(a2, w2s[hh][2], s);
        s = fmaf(a3, w2s[hh][3], s);
        x2v[hh] = fmaxf(s, 0.f);
    }
    float4* dst = (float4*)(x2out + r * 8);
    dst[0] = make_float4(x2v[0], x2v[1], x2v[2], x2v[3]);
    dst[1] = make_float4(x2v[4], x2v[5], x2v[6], x2v[7]);
}

// ---------------------------------------------------------------------------
// Kernel B: LSTM scanned over b (256 steps), 4096 independent t-columns.
// 32 lanes per column: lane = gate index g (i:0-7 f:8-15 g:16-23 o:24-31).
// ALL cross-lane traffic via __shfl (ds_bpermute) — no LDS, no ds_swizzle.
// Heads (18 actions + 1 value) fused, streamed to out.
// dones dtype is detected at runtime (bool may arrive as int32/byte/float).
// ---------------------------------------------------------------------------
__global__ __launch_bounds__(256) void lstm_head_kernel(
    const float* __restrict__ x2,
    const void* __restrict__ dones_raw,
    const float* __restrict__ hx,
    const float* __restrict__ Wih, const float* __restrict__ bih,
    const float* __restrict__ Whh, const float* __restrict__ bhh,
    const float* __restrict__ Wa, const float* __restrict__ ba,
    const float* __restrict__ Wv, const float* __restrict__ bv,
    float* __restrict__ out)
{
    int tid   = threadIdx.x;
    int g     = tid & 31;          // gate index within column
    int grp   = tid >> 5;          // 0..7 column group within block
    int t     = blockIdx.x * 8 + grp;
    int j     = g & 7;             // output element this gate feeds
    int wbase = tid & 32;          // which 32-lane half of the wave
    int gbase = wbase | j;         // wave-lane of the i-gate for j

    // ---- detect dones dtype from first 256 dwords (always in-bounds)
    // mode 0: int32 {0,1}; mode 1: packed bytes; mode 2: float {0,1.0f}
    __shared__ int s_flags;
    if (tid == 0) s_flags = 0;
    __syncthreads();
    {
        unsigned int v = ((const unsigned int*)dones_raw)[tid];
        int f = 0;
        if (v != 0u && v != 1u)           f |= 1;
        if (v != 0u && v != 0x3f800000u)  f |= 2;
        if (f) atomicOr(&s_flags, f);
    }
    __syncthreads();
    int flags = s_flags;
    int mode = ((flags & 1) == 0) ? 0 : (((flags & 2) == 0) ? 2 : 1);

    float wih[8], whh[8];
#pragma unroll
    for (int k = 0; k < 8; ++k) {
        wih[k] = Wih[g * 8 + k];
        whh[k] = Whh[g * 8 + k];
    }
    float gbias = bih[g] + bhh[g];

    // head weights: lanes 0..17 -> Wa rows, lane 18 -> Wv
    float hw[8]; float hb = 0.f;
#pragma unroll
    for (int k = 0; k < 8; ++k) hw[k] = 0.f;
    if (g < 18) {
#pragma unroll
        for (int k = 0; k < 8; ++k) hw[k] = Wa[g * 8 + k];
        hb = ba[g];
    } else if (g == 18) {
#pragma unroll
        for (int k = 0; k < 8; ++k) hw[k] = Wv[k];
        hb = bv[0];
    }

    // initial carry from hx: h = hx[0][t][:], c = hx[1][t][j]
    float h[8];
#pragma unroll
    for (int k = 0; k < 8; ++k) h[k] = hx[t * 8 + k];
    float c = hx[T_DIM * 8 + t * 8 + j];

    float* outA = out + (size_t)t * 18;                       // (b*T+t)*18, b=0
    float* outV = out + (size_t)18 * B_DIM * T_DIM + t;       // values block

    auto body = [&](auto MC) {
        constexpr int MODE = MC.value;
        const int*           di = (const int*)dones_raw;
        const unsigned char* db = (const unsigned char*)dones_raw;
        const float*         df = (const float*)dones_raw;
        auto rd_done = [&](int bb) -> int {
            size_t idx = (size_t)bb * T_DIM + t;
            if constexpr (MODE == 0) return di[idx];
            else if constexpr (MODE == 1) return (int)db[idx];
            else return (df[idx] != 0.f) ? 1 : 0;
        };

        // 4-deep prefetch of dones + x2 (named registers only)
        int d0, d1, d2, d3;
        float4 xa0, xb0, xa1, xb1, xa2, xb2, xa3, xb3;
        {
            const float4* xp;
            d0 = rd_done(0);
            xp = (const float4*)(x2 + ((size_t)0 * T_DIM + t) * 8); xa0 = xp[0]; xb0 = xp[1];
            d1 = rd_done(1);
            xp = (const float4*)(x2 + ((size_t)1 * T_DIM + t) * 8); xa1 = xp[0]; xb1 = xp[1];
            d2 = rd_done(2);
            xp = (const float4*)(x2 + ((size_t)2 * T_DIM + t) * 8); xa2 = xp[0]; xb2 = xp[1];
            d3 = rd_done(3);
            xp = (const float4*)(x2 + ((size_t)3 * T_DIM + t) * 8); xa3 = xp[0]; xb3 = xp[1];
        }

#define LSTM_STEP(BCUR, DPF, XA, XB)                                           \
    {                                                                          \
        int   done = DPF;                                                      \
        float4 va = XA, vb = XB;                                               \
        int bp = (BCUR) + 4;                                                   \
        if (bp < B_DIM) {                                                      \
            DPF = rd_done(bp);                                                 \
            const float4* xp = (const float4*)(x2 + ((size_t)bp * T_DIM + t) * 8); \
            XA = xp[0]; XB = xp[1];                                            \
        }                                                                      \
        float G0 = gbias;                                                      \
        G0 = fmaf(va.x, wih[0], G0); G0 = fmaf(va.y, wih[1], G0);              \
        G0 = fmaf(va.z, wih[2], G0); G0 = fmaf(va.w, wih[3], G0);              \
        G0 = fmaf(vb.x, wih[4], G0); G0 = fmaf(vb.y, wih[5], G0);              \
        G0 = fmaf(vb.z, wih[6], G0); G0 = fmaf(vb.w, wih[7], G0);              \
        float dh = h[0] * whh[0];                                              \
        dh = fmaf(h[1], whh[1], dh); dh = fmaf(h[2], whh[2], dh);              \
        dh = fmaf(h[3], whh[3], dh); dh = fmaf(h[4], whh[4], dh);              \
        dh = fmaf(h[5], whh[5], dh); dh = fmaf(h[6], whh[6], dh);              \
        dh = fmaf(h[7], whh[7], dh);                                           \
        float gate = done ? G0 : (G0 + dh);                                    \
        c = done ? 0.f : c;                                                    \
        bool isG = (g >= 16) && (g < 24);                                      \
        float y = isG ? 2.f * gate : gate;                                     \
        float e = __expf(-y);                                                  \
        float sg = 1.f / (1.f + e);                                            \
        float act = isG ? (2.f * sg - 1.f) : sg;                               \
        float fi = __shfl(act, gbase,      64);                                \
        float ff = __shfl(act, gbase | 8,  64);                                \
        float fg = __shfl(act, gbase | 16, 64);                                \
        float fo = __shfl(act, gbase | 24, 64);                                \
        float c2 = fmaf(ff, c, fi * fg);                                       \
        c = c2;                                                                \
        float e2 = __expf(-2.f * c2);                                          \
        float th = 2.f / (1.f + e2) - 1.f;                                     \
        float h2 = fo * th;                                                    \
        h[0] = __shfl(h2, wbase | 0, 64);                                      \
        h[1] = __shfl(h2, wbase | 1, 64);                                      \
        h[2] = __shfl(h2, wbase | 2, 64);                                      \
        h[3] = __shfl(h2, wbase | 3, 64);                                      \
        h[4] = __shfl(h2, wbase | 4, 64);                                      \
        h[5] = __shfl(h2, wbase | 5, 64);                                      \
        h[6] = __shfl(h2, wbase | 6, 64);                                      \
        h[7] = __shfl(h2, wbase | 7, 64);                                      \
        float o = hb;                                                          \
        o = fmaf(h[0], hw[0], o); o = fmaf(h[1], hw[1], o);                    \
        o = fmaf(h[2], hw[2], o); o = fmaf(h[3], hw[3], o);                    \
        o = fmaf(h[4], hw[4], o); o = fmaf(h[5], hw[5], o);                    \
        o = fmaf(h[6], hw[6], o); o = fmaf(h[7], hw[7], o);                    \
        if (g < 18) outA[g] = o;                                               \
        else if (g == 18) *outV = o;                                           \
        outA += (size_t)T_DIM * 18;                                            \
        outV += T_DIM;                                                         \
    }

        for (int b0 = 0; b0 < B_DIM; b0 += 4) {
            LSTM_STEP(b0 + 0, d0, xa0, xb0);
            LSTM_STEP(b0 + 1, d1, xa1, xb1);
            LSTM_STEP(b0 + 2, d2, xa2, xb2);
            LSTM_STEP(b0 + 3, d3, xa3, xb3);
        }
#undef LSTM_STEP
    };

    if (mode == 0)      body(IC<0>{});
    else if (mode == 1) body(IC<1>{});
    else                body(IC<2>{});
}

// ---------------------------------------------------------------------------
extern "C" void kernel_launch(void* const* d_in, const int* in_sizes, int n_in,
                              void* d_out, int out_size, void* d_ws, size_t ws_size,
                              hipStream_t stream) {
    (void)in_sizes; (void)n_in; (void)out_size; (void)ws_size;
    const float* states = (const float*)d_in[0];
    const void*  dones  = (const void*)d_in[1];
    const float* hx     = (const float*)d_in[2];
    const float* W1     = (const float*)d_in[3];
    const float* b1     = (const float*)d_in[4];
    const float* W2     = (const float*)d_in[5];
    const float* b2     = (const float*)d_in[6];
    const float* Wih    = (const float*)d_in[7];
    const float* bih    = (const float*)d_in[8];
    const float* Whh    = (const float*)d_in[9];
    const float* bhh    = (const float*)d_in[10];
    const float* Wa     = (const float*)d_in[11];
    const float* ba     = (const float*)d_in[12];
    const float* Wv     = (const float*)d_in[13];
    const float* bv     = (const float*)d_in[14];
    float* out = (float*)d_out;
    float* x2buf = (float*)d_ws;   // B*T*8 floats = 32 MiB scratch

    mlp_kernel<<<(B_DIM * T_DIM) / 256, 256, 0, stream>>>(states, W1, b1, W2, b2, x2buf);
    lstm_head_kernel<<<T_DIM / 8, 256, 0, stream>>>(x2buf, dones, hx, Wih, bih, Whh, bhh,
                                                    Wa, ba, Wv, bv, out);
}

// Round 4
// 193.709 us; speedup vs baseline: 1.1021x; 1.1021x over previous
//
#include <hip/hip_runtime.h>

// Problem constants (match reference)
#define T_DIM 4096
#define B_DIM 256
// N_OBS=64, H=8, N_ACT=18

// ---------------------------------------------------------------------------
// Kernel A: fused MLP  states(B,T,64) -> x1(4) -> x2(B,T,8), relu
// LDS-staged fully-coalesced reads: each wave stages 16 rows (4 KB) via 4
// contiguous 1 KB wave-loads; 4 lanes per row compute partial dots and
// butterfly-reduce. Block = 64 rows. LDS row stride padded to 17 float4.
// ---------------------------------------------------------------------------
__global__ __launch_bounds__(256) void mlp_kernel(
    const float* __restrict__ states,
    const float* __restrict__ W1, const float* __restrict__ b1,
    const float* __restrict__ W2, const float* __restrict__ b2,
    float* __restrict__ x2out)
{
    __shared__ float4 w1s4[4][16];      // W1 rows as float4
    __shared__ float  w2s[8][4];
    __shared__ float  b1s[4];
    __shared__ float  b2s[8];
    __shared__ float4 stage[4][16 * 17]; // per-wave 16 rows, stride 17 slots

    int tid = threadIdx.x;
    ((float*)w1s4)[tid] = W1[tid];              // 256 floats
    if (tid < 32) ((float*)w2s)[tid] = W2[tid];
    if (tid < 4)  b1s[tid] = b1[tid];
    if (tid >= 8 && tid < 16) b2s[tid - 8] = b2[tid - 8];

    int w = tid >> 6;        // wave 0..3
    int l = tid & 63;        // lane

    // stage 16 rows per wave: 4 contiguous 1KB wave-loads
    const float4* src4 = (const float4*)states;
    size_t base_f4 = ((size_t)blockIdx.x * 64 + (size_t)w * 16) * 16;
#pragma unroll
    for (int k = 0; k < 4; ++k) {
        int idx = k * 64 + l;            // 0..255 within the 16-row tile
        int row = idx >> 4, m = idx & 15;
        stage[w][row * 17 + m] = src4[base_f4 + idx];
    }
    __syncthreads();

    // compute: 4 lanes per row, lane q owns obs [q*16, q*16+16)
    int rl = l >> 2;         // row within wave tile 0..15
    int q  = l & 3;
    const float4* rowp = &stage[w][rl * 17];

    float a0 = 0.f, a1 = 0.f, a2 = 0.f, a3 = 0.f;
#pragma unroll
    for (int kk = 0; kk < 4; ++kk) {
        float4 v = rowp[q * 4 + kk];
        float4 w0 = w1s4[0][q * 4 + kk];
        float4 w1v = w1s4[1][q * 4 + kk];
        float4 w2v = w1s4[2][q * 4 + kk];
        float4 w3v = w1s4[3][q * 4 + kk];
        a0 = fmaf(v.x, w0.x, a0); a0 = fmaf(v.y, w0.y, a0);
        a0 = fmaf(v.z, w0.z, a0); a0 = fmaf(v.w, w0.w, a0);
        a1 = fmaf(v.x, w1v.x, a1); a1 = fmaf(v.y, w1v.y, a1);
        a1 = fmaf(v.z, w1v.z, a1); a1 = fmaf(v.w, w1v.w, a1);
        a2 = fmaf(v.x, w2v.x, a2); a2 = fmaf(v.y, w2v.y, a2);
        a2 = fmaf(v.z, w2v.z, a2); a2 = fmaf(v.w, w2v.w, a2);
        a3 = fmaf(v.x, w3v.x, a3); a3 = fmaf(v.y, w3v.y, a3);
        a3 = fmaf(v.z, w3v.z, a3); a3 = fmaf(v.w, w3v.w, a3);
    }
    // butterfly reduce across the 4 lanes of this row
    a0 += __shfl_xor(a0, 1, 64); a1 += __shfl_xor(a1, 1, 64);
    a2 += __shfl_xor(a2, 1, 64); a3 += __shfl_xor(a3, 1, 64);
    a0 += __shfl_xor(a0, 2, 64); a1 += __shfl_xor(a1, 2, 64);
    a2 += __shfl_xor(a2, 2, 64); a3 += __shfl_xor(a3, 2, 64);

    a0 = fmaxf(a0 + b1s[0], 0.f);
    a1 = fmaxf(a1 + b1s[1], 0.f);
    a2 = fmaxf(a2 + b1s[2], 0.f);
    a3 = fmaxf(a3 + b1s[3], 0.f);

    // lane q produces x2 elements 2q, 2q+1
    int h0 = 2 * q, h1 = 2 * q + 1;
    float s0 = b2s[h0];
    s0 = fmaf(a0, w2s[h0][0], s0); s0 = fmaf(a1, w2s[h0][1], s0);
    s0 = fmaf(a2, w2s[h0][2], s0); s0 = fmaf(a3, w2s[h0][3], s0);
    float s1 = b2s[h1];
    s1 = fmaf(a0, w2s[h1][0], s1); s1 = fmaf(a1, w2s[h1][1], s1);
    s1 = fmaf(a2, w2s[h1][2], s1); s1 = fmaf(a3, w2s[h1][3], s1);
    s0 = fmaxf(s0, 0.f);
    s1 = fmaxf(s1, 0.f);

    size_t r = (size_t)blockIdx.x * 64 + (size_t)w * 16 + rl;
    ((float2*)x2out)[r * 4 + q] = make_float2(s0, s1);
}

// ---------------------------------------------------------------------------
// Kernel B: LSTM scanned over b (256 steps), 4096 independent t-columns.
// 32 lanes per column: lane = gate index g (i:0-7 f:8-15 g:16-23 o:24-31).
// ALL cross-lane traffic via __shfl — no LDS. Heads fused, streamed to out.
// dones confirmed int32 on device (R1/R2 experiment).
// ---------------------------------------------------------------------------
__global__ __launch_bounds__(256) void lstm_head_kernel(
    const float* __restrict__ x2,
    const int* __restrict__ dones,
    const float* __restrict__ hx,
    const float* __restrict__ Wih, const float* __restrict__ bih,
    const float* __restrict__ Whh, const float* __restrict__ bhh,
    const float* __restrict__ Wa, const float* __restrict__ ba,
    const float* __restrict__ Wv, const float* __restrict__ bv,
    float* __restrict__ out)
{
    int tid   = threadIdx.x;
    int g     = tid & 31;          // gate index within column
    int grp   = tid >> 5;          // 0..7 column group within block
    int t     = blockIdx.x * 8 + grp;
    int j     = g & 7;             // output element this gate feeds
    int wbase = tid & 32;          // which 32-lane half of the wave
    int gbase = wbase | j;         // wave-lane of the i-gate for j

    float wih[8], whh[8];
#pragma unroll
    for (int k = 0; k < 8; ++k) {
        wih[k] = Wih[g * 8 + k];
        whh[k] = Whh[g * 8 + k];
    }
    float gbias = bih[g] + bhh[g];

    // head weights: lanes 0..17 -> Wa rows, lane 18 -> Wv
    float hw[8]; float hb = 0.f;
#pragma unroll
    for (int k = 0; k < 8; ++k) hw[k] = 0.f;
    if (g < 18) {
#pragma unroll
        for (int k = 0; k < 8; ++k) hw[k] = Wa[g * 8 + k];
        hb = ba[g];
    } else if (g == 18) {
#pragma unroll
        for (int k = 0; k < 8; ++k) hw[k] = Wv[k];
        hb = bv[0];
    }

    // initial carry from hx: h = hx[0][t][:], c = hx[1][t][j]
    float h[8];
#pragma unroll
    for (int k = 0; k < 8; ++k) h[k] = hx[t * 8 + k];
    float c = hx[T_DIM * 8 + t * 8 + j];

    float* outA = out + (size_t)t * 18;                       // (b*T+t)*18, b=0
    float* outV = out + (size_t)18 * B_DIM * T_DIM + t;       // values block

    // 4-deep prefetch of dones + x2 (named registers only)
    int d0, d1, d2, d3;
    float4 xa0, xb0, xa1, xb1, xa2, xb2, xa3, xb3;
    {
        const float4* xp;
        d0 = dones[(size_t)0 * T_DIM + t];
        xp = (const float4*)(x2 + ((size_t)0 * T_DIM + t) * 8); xa0 = xp[0]; xb0 = xp[1];
        d1 = dones[(size_t)1 * T_DIM + t];
        xp = (const float4*)(x2 + ((size_t)1 * T_DIM + t) * 8); xa1 = xp[0]; xb1 = xp[1];
        d2 = dones[(size_t)2 * T_DIM + t];
        xp = (const float4*)(x2 + ((size_t)2 * T_DIM + t) * 8); xa2 = xp[0]; xb2 = xp[1];
        d3 = dones[(size_t)3 * T_DIM + t];
        xp = (const float4*)(x2 + ((size_t)3 * T_DIM + t) * 8); xa3 = xp[0]; xb3 = xp[1];
    }

#define LSTM_STEP(BCUR, DPF, XA, XB)                                           \
    {                                                                          \
        int   done = DPF;                                                      \
        float4 va = XA, vb = XB;                                               \
        int bp = (BCUR) + 4;                                                   \
        if (bp < B_DIM) {                                                      \
            DPF = dones[(size_t)bp * T_DIM + t];                               \
            const float4* xp = (const float4*)(x2 + ((size_t)bp * T_DIM + t) * 8); \
            XA = xp[0]; XB = xp[1];                                            \
        }                                                                      \
        float G0 = gbias;                                                      \
        G0 = fmaf(va.x, wih[0], G0); G0 = fmaf(va.y, wih[1], G0);              \
        G0 = fmaf(va.z, wih[2], G0); G0 = fmaf(va.w, wih[3], G0);              \
        G0 = fmaf(vb.x, wih[4], G0); G0 = fmaf(vb.y, wih[5], G0);              \
        G0 = fmaf(vb.z, wih[6], G0); G0 = fmaf(vb.w, wih[7], G0);              \
        float dh = h[0] * whh[0];                                              \
        dh = fmaf(h[1], whh[1], dh); dh = fmaf(h[2], whh[2], dh);              \
        dh = fmaf(h[3], whh[3], dh); dh = fmaf(h[4], whh[4], dh);              \
        dh = fmaf(h[5], whh[5], dh); dh = fmaf(h[6], whh[6], dh);              \
        dh = fmaf(h[7], whh[7], dh);                                           \
        float gate = done ? G0 : (G0 + dh);                                    \
        c = done ? 0.f : c;                                                    \
        bool isG = (g >= 16) && (g < 24);                                      \
        float y = isG ? 2.f * gate : gate;                                     \
        float e = __expf(-y);                                                  \
        float sg = 1.f / (1.f + e);                                            \
        float act = isG ? (2.f * sg - 1.f) : sg;                               \
        float fi = __shfl(act, gbase,      64);                                \
        float ff = __shfl(act, gbase | 8,  64);                                \
        float fg = __shfl(act, gbase | 16, 64);                                \
        float fo = __shfl(act, gbase | 24, 64);                                \
        float c2 = fmaf(ff, c, fi * fg);                                       \
        c = c2;                                                                \
        float e2 = __expf(-2.f * c2);                                          \
        float th = 2.f / (1.f + e2) - 1.f;                                     \
        float h2 = fo * th;                                                    \
        h[0] = __shfl(h2, wbase | 0, 64);                                      \
        h[1] = __shfl(h2, wbase | 1, 64);                                      \
        h[2] = __shfl(h2, wbase | 2, 64);                                      \
        h[3] = __shfl(h2, wbase | 3, 64);                                      \
        h[4] = __shfl(h2, wbase | 4, 64);                                      \
        h[5] = __shfl(h2, wbase | 5, 64);                                      \
        h[6] = __shfl(h2, wbase | 6, 64);                                      \
        h[7] = __shfl(h2, wbase | 7, 64);                                      \
        float o = hb;                                                          \
        o = fmaf(h[0], hw[0], o); o = fmaf(h[1], hw[1], o);                    \
        o = fmaf(h[2], hw[2], o); o = fmaf(h[3], hw[3], o);                    \
        o = fmaf(h[4], hw[4], o); o = fmaf(h[5], hw[5], o);                    \
        o = fmaf(h[6], hw[6], o); o = fmaf(h[7], hw[7], o);                    \
        if (g < 18) outA[g] = o;                                               \
        else if (g == 18) *outV = o;                                           \
        outA += (size_t)T_DIM * 18;                                            \
        outV += T_DIM;                                                         \
    }

    for (int b0 = 0; b0 < B_DIM; b0 += 4) {
        LSTM_STEP(b0 + 0, d0, xa0, xb0);
        LSTM_STEP(b0 + 1, d1, xa1, xb1);
        LSTM_STEP(b0 + 2, d2, xa2, xb2);
        LSTM_STEP(b0 + 3, d3, xa3, xb3);
    }
#undef LSTM_STEP
}

// ---------------------------------------------------------------------------
extern "C" void kernel_launch(void* const* d_in, const int* in_sizes, int n_in,
                              void* d_out, int out_size, void* d_ws, size_t ws_size,
                              hipStream_t stream) {
    (void)in_sizes; (void)n_in; (void)out_size; (void)ws_size;
    const float* states = (const float*)d_in[0];
    const int*   dones  = (const int*)d_in[1];
    const float* hx     = (const float*)d_in[2];
    const float* W1     = (const float*)d_in[3];
    const float* b1     = (const float*)d_in[4];
    const float* W2     = (const float*)d_in[5];
    const float* b2     = (const float*)d_in[6];
    const float* Wih    = (const float*)d_in[7];
    const float* bih    = (const float*)d_in[8];
    const float* Whh    = (const float*)d_in[9];
    const float* bhh    = (const float*)d_in[10];
    const float* Wa     = (const float*)d_in[11];
    const float* ba     = (const float*)d_in[12];
    const float* Wv     = (const float*)d_in[13];
    const float* bv     = (const float*)d_in[14];
    float* out = (float*)d_out;
    float* x2buf = (float*)d_ws;   // B*T*8 floats = 32 MiB scratch

    mlp_kernel<<<(B_DIM * T_DIM) / 64, 256, 0, stream>>>(states, W1, b1, W2, b2, x2buf);
    lstm_head_kernel<<<T_DIM / 8, 256, 0, stream>>>(x2buf, dones, hx, Wih, bih, Whh, bhh,
                                                    Wa, ba, Wv, bv, out);
}